// Round 2
// baseline (523.634 us; speedup 1.0000x reference)
//
#include <hip/hip_runtime.h>
#include <hip/hip_bf16.h>
#include <stdint.h>

#define B_    64
#define S_    2048
#define ENC_  512
#define ATTN_ 256

typedef __bf16 bf16;
typedef bf16  bf16x8 __attribute__((ext_vector_type(8)));
typedef float f32x4  __attribute__((ext_vector_type(4)));

__device__ __forceinline__ float fexp2(float x) {
#if __has_builtin(__builtin_amdgcn_exp2f)
    return __builtin_amdgcn_exp2f(x);
#else
    return exp2f(x);
#endif
}
__device__ __forceinline__ float frcp(float x) {
#if __has_builtin(__builtin_amdgcn_rcpf)
    return __builtin_amdgcn_rcpf(x);
#else
    return 1.0f / x;
#endif
}
// tanh(x) = 1 - 2/(e^{2x}+1); overflow-safe (exp2->inf => 1, ->0 => -1)
__device__ __forceinline__ float fast_tanh(float x) {
    float e = fexp2(x * 2.8853900817779268f);
    return 1.0f - 2.0f * frcp(e + 1.0f);
}

// ---------------- setup: WT transpose->bf16 (blocks 0..511) + dec_proj (512..575)
__global__ __launch_bounds__(256) void k_setup(const float* __restrict__ W_enc,
                                               const float* __restrict__ dec_state,
                                               const float* __restrict__ W_dec,
                                               bf16* __restrict__ WT,
                                               float* __restrict__ dp) {
    int blk = blockIdx.x;
    if (blk < 512) {
        int idx = blk * 256 + threadIdx.x;      // 0..131071
        int n = idx >> 9;                        // /512
        int k = idx & 511;
        WT[idx] = (bf16)W_enc[k * ATTN_ + n];    // coalesced writes
    } else {
        int b = blk - 512;
        int a = threadIdx.x;
        const float* ds = dec_state + b * 512;
        float acc = 0.f;
#pragma unroll 8
        for (int d = 0; d < 512; ++d)
            acc += ds[d] * W_dec[d * ATTN_ + a];
        dp[b * ATTN_ + a] = acc;
    }
}

// ---------------- scores: GEMM(M=131072,K=512,N=256) + tanh.v epilogue ----
// Barrier-free / LDS-free. Block = 4 independent waves, wave = 32 rows x 256 cols.
// A frags straight from global fp32 (lane l15 = row, q = k-quad), cvt to bf16.
// B frags straight from L2-resident WT (lane l15 = col, q = k-quad).
__global__ __launch_bounds__(256, 2) void k_scores(
    const float* __restrict__ enc,    // [131072][512]
    const bf16*  __restrict__ WT,     // [256][512] (n-major)
    const float* __restrict__ dp,     // [64][256]
    const float* __restrict__ v,      // [256]
    float* __restrict__ out_scores)   // [131072]
{
    const int tid  = threadIdx.x;
    const int wave = tid >> 6;
    const int lane = tid & 63;
    const int l15  = lane & 15;
    const int q    = lane >> 4;
    const int row0 = blockIdx.x * 128 + wave * 32;   // wave's first row
    const int b    = row0 >> 11;                     // row / 2048 (uniform per block)

    const f32x4 zero4 = {0.f, 0.f, 0.f, 0.f};
    f32x4 acc[2][16];
#pragma unroll
    for (int mt = 0; mt < 2; ++mt)
#pragma unroll
        for (int nt = 0; nt < 16; ++nt)
            acc[mt][nt] = zero4;

    const float* ag0 = enc + (size_t)(row0 + l15) * 512 + q * 8;        // mt=0 row
    const float* ag1 = ag0 + 16 * 512;                                   // mt=1 row
    const bf16*  bg  = WT + (size_t)l15 * 512 + q * 8;                   // col base

    // software prefetch of A one K-step ahead (hides HBM latency under MFMA)
    float4 a0 = *(const float4*)(ag0);
    float4 a1 = *(const float4*)(ag0 + 4);
    float4 a2 = *(const float4*)(ag1);
    float4 a3 = *(const float4*)(ag1 + 4);

    for (int ks = 0; ks < 16; ++ks) {
        int ksn = (ks < 15) ? (ks + 1) : 15;
        float4 n0 = *(const float4*)(ag0 + ksn * 32);
        float4 n1 = *(const float4*)(ag0 + ksn * 32 + 4);
        float4 n2 = *(const float4*)(ag1 + ksn * 32);
        float4 n3 = *(const float4*)(ag1 + ksn * 32 + 4);

        bf16x8 af0, af1;
        af0[0]=(bf16)a0.x; af0[1]=(bf16)a0.y; af0[2]=(bf16)a0.z; af0[3]=(bf16)a0.w;
        af0[4]=(bf16)a1.x; af0[5]=(bf16)a1.y; af0[6]=(bf16)a1.z; af0[7]=(bf16)a1.w;
        af1[0]=(bf16)a2.x; af1[1]=(bf16)a2.y; af1[2]=(bf16)a2.z; af1[3]=(bf16)a2.w;
        af1[4]=(bf16)a3.x; af1[5]=(bf16)a3.y; af1[6]=(bf16)a3.z; af1[7]=(bf16)a3.w;

#pragma unroll
        for (int h = 0; h < 2; ++h) {
            bf16x8 bfr[8];
#pragma unroll
            for (int j = 0; j < 8; ++j) {
                int nt = h * 8 + j;
                bfr[j] = *(const bf16x8*)(bg + (size_t)nt * 16 * 512 + ks * 32);
            }
#pragma unroll
            for (int j = 0; j < 8; ++j) {
                int nt = h * 8 + j;
                acc[0][nt] = __builtin_amdgcn_mfma_f32_16x16x32_bf16(af0, bfr[j], acc[0][nt], 0, 0, 0);
                acc[1][nt] = __builtin_amdgcn_mfma_f32_16x16x32_bf16(af1, bfr[j], acc[1][nt], 0, 0, 0);
            }
        }
        a0 = n0; a1 = n1; a2 = n2; a3 = n3;
    }

    // ---- epilogue: scores[row] = sum_col tanh(C + dp[col]) * v[col] ----
    // C/D layout: col = l15 + 16*nt, row_local = q*4 + reg
    float dpv[16], vv[16];
#pragma unroll
    for (int nt = 0; nt < 16; ++nt) {
        int col = nt * 16 + l15;
        dpv[nt] = dp[b * 256 + col];
        vv[nt]  = v[col];
    }
#pragma unroll
    for (int mt = 0; mt < 2; ++mt) {
#pragma unroll
        for (int r = 0; r < 4; ++r) {
            float s = 0.f;
#pragma unroll
            for (int nt = 0; nt < 16; ++nt)
                s += fast_tanh(acc[mt][nt][r] + dpv[nt]) * vv[nt];
            s += __shfl_xor(s, 1, 16);
            s += __shfl_xor(s, 2, 16);
            s += __shfl_xor(s, 4, 16);
            s += __shfl_xor(s, 8, 16);
            if (l15 == 0)
                out_scores[row0 + mt * 16 + q * 4 + r] = s;
        }
    }
}

// ---------------- softmax over S per batch, in place in d_out --------------
__global__ __launch_bounds__(256) void k_softmax(float* __restrict__ attn) {
    int b = blockIdx.x;
    float* s = attn + b * 2048;
    __shared__ float red[256];
    int tid = threadIdx.x;

    float x[8];
    float mx = -1e30f;
#pragma unroll
    for (int i = 0; i < 8; ++i) { x[i] = s[tid + 256 * i]; mx = fmaxf(mx, x[i]); }
    red[tid] = mx;
    __syncthreads();
    for (int off = 128; off > 0; off >>= 1) {
        if (tid < off) red[tid] = fmaxf(red[tid], red[tid + off]);
        __syncthreads();
    }
    mx = red[0];
    __syncthreads();

    float e[8];
    float lsum = 0.f;
#pragma unroll
    for (int i = 0; i < 8; ++i) { e[i] = fexp2((x[i] - mx) * 1.4426950408889634f); lsum += e[i]; }
    red[tid] = lsum;
    __syncthreads();
    for (int off = 128; off > 0; off >>= 1) {
        if (tid < off) red[tid] += red[tid + off];
        __syncthreads();
    }
    float inv = 1.0f / red[0];
#pragma unroll
    for (int i = 0; i < 8; ++i) s[tid + 256 * i] = e[i] * inv;
}

// ---------------- context pass 1: per-slab partials ------------------------
// grid = 64 b x 8 slabs (256 rows each). Block streams a contiguous 512 KB slab.
__global__ __launch_bounds__(256) void k_context(const float* __restrict__ enc,
                                                 const float* __restrict__ attn,
                                                 float* __restrict__ partial) {
    int b    = blockIdx.x >> 3;
    int slab = blockIdx.x & 7;
    int tid  = threadIdx.x;
    int eq   = tid & 127;                 // e = eq*4 (float4)
    int sr   = tid >> 7;                  // 0/1 — wave-uniform
    const float* eb = enc + ((size_t)b * 2048 + slab * 256) * 512;
    const float* w  = attn + b * 2048 + slab * 256;

    f32x4 acc = {0.f, 0.f, 0.f, 0.f};
#pragma unroll 4
    for (int s = sr; s < 256; s += 2) {
        float ws = w[s];
        f32x4 ev = *(const f32x4*)(eb + (size_t)s * 512 + eq * 4);
        acc += ev * ws;
    }
    __shared__ f32x4 red[128];
    if (sr) red[eq] = acc;
    __syncthreads();
    if (!sr) {
        acc += red[eq];
        *(f32x4*)(partial + (size_t)blockIdx.x * 512 + eq * 4) = acc;
    }
}

// ---------------- context pass 2: reduce 8 slabs ---------------------------
__global__ __launch_bounds__(128) void k_ctxred(const float* __restrict__ partial,
                                                float* __restrict__ ctx) {
    int b  = blockIdx.x;
    int eq = threadIdx.x;                 // e = eq*4
    f32x4 a = {0.f, 0.f, 0.f, 0.f};
#pragma unroll
    for (int slab = 0; slab < 8; ++slab)
        a += *(const f32x4*)(partial + ((size_t)b * 8 + slab) * 512 + eq * 4);
    *(f32x4*)(ctx + b * 512 + eq * 4) = a;
}

extern "C" void kernel_launch(void* const* d_in, const int* in_sizes, int n_in,
                              void* d_out, int out_size, void* d_ws, size_t ws_size,
                              hipStream_t stream) {
    const float* enc       = (const float*)d_in[0];
    const float* dec_state = (const float*)d_in[1];
    const float* W_enc     = (const float*)d_in[2];
    const float* W_dec     = (const float*)d_in[3];
    const float* v         = (const float*)d_in[4];

    float* ctx  = (float*)d_out;                 // [64,512]
    float* attn = (float*)d_out + 64 * 512;      // [64,2048] (scores -> softmax in place)

    // workspace: WT bf16 256KB | dp fp32 64KB | partials fp32 1MB
    char*  ws      = (char*)d_ws;
    bf16*  WT      = (bf16*)ws;
    float* dp      = (float*)(ws + 256 * 1024);
    float* partial = (float*)(ws + 256 * 1024 + 64 * 1024);

    k_setup  <<<576, 256, 0, stream>>>(W_enc, dec_state, W_dec, WT, dp);
    k_scores <<<1024, 256, 0, stream>>>(enc, WT, dp, v, attn);
    k_softmax<<<64, 256, 0, stream>>>(attn);
    k_context<<<512, 256, 0, stream>>>(enc, attn, partial);
    k_ctxred <<<64, 128, 0, stream>>>(partial, ctx);
}

// Round 3
// 449.909 us; speedup vs baseline: 1.1639x; 1.1639x over previous
//
#include <hip/hip_runtime.h>
#include <hip/hip_bf16.h>
#include <stdint.h>

#define B_    64
#define S_    2048
#define ENC_  512
#define ATTN_ 256

typedef __bf16 bf16;
typedef bf16  bf16x8 __attribute__((ext_vector_type(8)));
typedef float f32x4  __attribute__((ext_vector_type(4)));

__device__ __forceinline__ float fexp2(float x) {
#if __has_builtin(__builtin_amdgcn_exp2f)
    return __builtin_amdgcn_exp2f(x);
#else
    return exp2f(x);
#endif
}
__device__ __forceinline__ float frcp(float x) {
#if __has_builtin(__builtin_amdgcn_rcpf)
    return __builtin_amdgcn_rcpf(x);
#else
    return 1.0f / x;
#endif
}
// tanh(x) = 1 - 2/(e^{2x}+1); overflow-safe (exp2->inf => 1, ->0 => -1)
__device__ __forceinline__ float fast_tanh(float x) {
    float e = fexp2(x * 2.8853900817779268f);
    return 1.0f - 2.0f * frcp(e + 1.0f);
}

__device__ __forceinline__ void async_copy16(const void* g, void* l) {
#if __has_builtin(__builtin_amdgcn_global_load_lds)
    __builtin_amdgcn_global_load_lds(
        (__attribute__((address_space(1))) void*)(g),
        (__attribute__((address_space(3))) void*)(l), 16, 0, 0);
#else
    *(uint4*)l = *(const uint4*)g;
#endif
}

// ---------------- setup: WT transpose->bf16 (blocks 0..511) + dec_proj (512..575)
__global__ __launch_bounds__(256) void k_setup(const float* __restrict__ W_enc,
                                               const float* __restrict__ dec_state,
                                               const float* __restrict__ W_dec,
                                               bf16* __restrict__ WT,
                                               float* __restrict__ dp) {
    int blk = blockIdx.x;
    if (blk < 512) {
        int idx = blk * 256 + threadIdx.x;      // 0..131071
        int n = idx >> 9;                        // /512
        int k = idx & 511;
        WT[idx] = (bf16)W_enc[k * ATTN_ + n];    // coalesced writes
    } else {
        int b = blk - 512;
        int a = threadIdx.x;
        const float* ds = dec_state + b * 512;
        float acc = 0.f;
#pragma unroll 8
        for (int d = 0; d < 512; ++d)
            acc += ds[d] * W_dec[d * ATTN_ + a];
        dp[b * ATTN_ + a] = acc;
    }
}

// ---------------- scores: GEMM(M=131072,K=512,N=256) + tanh.v epilogue ----
// m97 structure: LDS-staged, 2 barriers/K-step. Block tile M=128 x N=256,
// K-step 32, 4 waves as 2(m) x 2(n); wave = 64 rows x 128 cols.
// A: fp32->bf16 convert into padded LDS (stride 40 elems, <=2-way banks).
// B: global_load_lds width16 from L2-resident WT, XOR chunk swizzle
//    t(c)=(c+(c>>2))&3 -> <=2-way banks on the fragment reads.
__global__ __launch_bounds__(256, 2) void k_scores(
    const float* __restrict__ enc,    // [131072][512]
    const bf16*  __restrict__ WT,     // [256][512] (n-major)
    const float* __restrict__ dp,     // [64][256]
    const float* __restrict__ v,      // [256]
    float* __restrict__ out_scores)   // [131072]
{
    __shared__ __align__(16) bf16 As[128 * 40];   // 10.0 KB, padded rows
    __shared__ __align__(16) bf16 Bs[256 * 32];   // 16.0 KB, swizzled chunks
    __shared__ float partial[4][64];

    const int tid  = threadIdx.x;
    const int wave = tid >> 6;
    const int lane = tid & 63;
    const int l15  = lane & 15;
    const int q    = lane >> 4;
    const int m0   = blockIdx.x * 128;
    const int b    = blockIdx.x >> 4;            // 16 blocks per batch row-range

    const int mrow0 = (wave >> 1) * 64;
    const int ncol0 = (wave & 1) * 128;

    // preload dp & v for this wave's 8 column groups
    float dpv[8], vv[8];
#pragma unroll
    for (int nt = 0; nt < 8; ++nt) {
        int col = ncol0 + nt * 16 + l15;
        dpv[nt] = dp[b * 256 + col];
        vv[nt]  = v[col];
    }

    const f32x4 zero4 = {0.f, 0.f, 0.f, 0.f};
    f32x4 acc[4][8];
#pragma unroll
    for (int mt = 0; mt < 4; ++mt)
#pragma unroll
        for (int nt = 0; nt < 8; ++nt)
            acc[mt][nt] = zero4;

    // A staging: thread t -> row t>>1, k-half (t&1)*16 floats
    const int arow = tid >> 1;
    const int akc  = tid & 1;
    const float* ag = enc + (size_t)(m0 + arow) * 512 + akc * 16;
    bf16* as_dst = &As[arow * 40 + akc * 16];

    // B staging: round r -> col c = r*64 + (t>>2), chunk slot t&3
    const int bcol4 = tid >> 2;
    const int bslot = tid & 3;

    for (int ks = 0; ks < 16; ++ks) {
        // ---- B: async global->LDS, contiguous dst = base + tid*16B ----
#pragma unroll
        for (int r = 0; r < 4; ++r) {
            int c = r * 64 + bcol4;
            int g = bslot ^ ((c + (c >> 2)) & 3);     // fetch swizzled chunk
            async_copy16(WT + (size_t)c * 512 + ks * 32 + g * 8,
                         &Bs[r * 2048 + tid * 8]);
        }
        // ---- A: fp32 load, cvt to bf16, padded ds_write_b128 x2 ----
        {
            const float* s = ag + ks * 32;
            float4 f0 = *(const float4*)(s);
            float4 f1 = *(const float4*)(s + 4);
            float4 f2 = *(const float4*)(s + 8);
            float4 f3 = *(const float4*)(s + 12);
            bf16x8 lo, hi;
            lo[0]=(bf16)f0.x; lo[1]=(bf16)f0.y; lo[2]=(bf16)f0.z; lo[3]=(bf16)f0.w;
            lo[4]=(bf16)f1.x; lo[5]=(bf16)f1.y; lo[6]=(bf16)f1.z; lo[7]=(bf16)f1.w;
            hi[0]=(bf16)f2.x; hi[1]=(bf16)f2.y; hi[2]=(bf16)f2.z; hi[3]=(bf16)f2.w;
            hi[4]=(bf16)f3.x; hi[5]=(bf16)f3.y; hi[6]=(bf16)f3.z; hi[7]=(bf16)f3.w;
            *(bf16x8*)(as_dst)     = lo;
            *(bf16x8*)(as_dst + 8) = hi;
        }
        __syncthreads();

        // ---- fragments ----
        bf16x8 af[4];
#pragma unroll
        for (int mt = 0; mt < 4; ++mt) {
            int row = mrow0 + mt * 16 + l15;
            af[mt] = *(const bf16x8*)(&As[row * 40 + q * 8]);
        }
        bf16x8 bfr[8];
#pragma unroll
        for (int nt = 0; nt < 8; ++nt) {
            int col = ncol0 + nt * 16 + l15;
            int p = q ^ ((col + (col >> 2)) & 3);
            bfr[nt] = *(const bf16x8*)(&Bs[col * 32 + p * 8]);
        }
#pragma unroll
        for (int mt = 0; mt < 4; ++mt)
#pragma unroll
            for (int nt = 0; nt < 8; ++nt)
                acc[mt][nt] = __builtin_amdgcn_mfma_f32_16x16x32_bf16(af[mt], bfr[nt], acc[mt][nt], 0, 0, 0);
        __syncthreads();
    }

    // ---- epilogue: scores[row] = sum_col tanh(C + dp[col]) * v[col] ----
    // C/D layout: col = l15 + 16*nt, row_local = q*4 + reg
#pragma unroll
    for (int mt = 0; mt < 4; ++mt) {
#pragma unroll
        for (int r = 0; r < 4; ++r) {
            float s = 0.f;
#pragma unroll
            for (int nt = 0; nt < 8; ++nt)
                s += fast_tanh(acc[mt][nt][r] + dpv[nt]) * vv[nt];
            s += __shfl_xor(s, 1, 16);
            s += __shfl_xor(s, 2, 16);
            s += __shfl_xor(s, 4, 16);
            s += __shfl_xor(s, 8, 16);
            if (l15 == 0)
                partial[wave][mt * 16 + q * 4 + r] = s;
        }
    }
    __syncthreads();
    if (tid < 128) {
        int mw   = tid >> 6;
        int rloc = tid & 63;
        out_scores[m0 + mw * 64 + rloc] =
            partial[mw * 2][rloc] + partial[mw * 2 + 1][rloc];
    }
}

// ---------------- softmax over S per batch, in place in d_out --------------
__global__ __launch_bounds__(256) void k_softmax(float* __restrict__ attn) {
    int b = blockIdx.x;
    float* s = attn + b * 2048;
    __shared__ float red[256];
    int tid = threadIdx.x;

    float x[8];
    float mx = -1e30f;
#pragma unroll
    for (int i = 0; i < 8; ++i) { x[i] = s[tid + 256 * i]; mx = fmaxf(mx, x[i]); }
    red[tid] = mx;
    __syncthreads();
    for (int off = 128; off > 0; off >>= 1) {
        if (tid < off) red[tid] = fmaxf(red[tid], red[tid + off]);
        __syncthreads();
    }
    mx = red[0];
    __syncthreads();

    float e[8];
    float lsum = 0.f;
#pragma unroll
    for (int i = 0; i < 8; ++i) { e[i] = fexp2((x[i] - mx) * 1.4426950408889634f); lsum += e[i]; }
    red[tid] = lsum;
    __syncthreads();
    for (int off = 128; off > 0; off >>= 1) {
        if (tid < off) red[tid] += red[tid + off];
        __syncthreads();
    }
    float inv = 1.0f / red[0];
#pragma unroll
    for (int i = 0; i < 8; ++i) s[tid + 256 * i] = e[i] * inv;
}

// ---------------- context pass 1: per-slab partials ------------------------
// grid = 64 b x 8 slabs (256 rows each). Block streams a contiguous 512 KB slab.
__global__ __launch_bounds__(256) void k_context(const float* __restrict__ enc,
                                                 const float* __restrict__ attn,
                                                 float* __restrict__ partial) {
    int b    = blockIdx.x >> 3;
    int slab = blockIdx.x & 7;
    int tid  = threadIdx.x;
    int eq   = tid & 127;                 // e = eq*4 (float4)
    int sr   = tid >> 7;                  // 0/1 — wave-uniform
    const float* eb = enc + ((size_t)b * 2048 + slab * 256) * 512;
    const float* w  = attn + b * 2048 + slab * 256;

    f32x4 acc = {0.f, 0.f, 0.f, 0.f};
#pragma unroll 4
    for (int s = sr; s < 256; s += 2) {
        float ws = w[s];
        f32x4 ev = *(const f32x4*)(eb + (size_t)s * 512 + eq * 4);
        acc += ev * ws;
    }
    __shared__ f32x4 red[128];
    if (sr) red[eq] = acc;
    __syncthreads();
    if (!sr) {
        acc += red[eq];
        *(f32x4*)(partial + (size_t)blockIdx.x * 512 + eq * 4) = acc;
    }
}

// ---------------- context pass 2: reduce 8 slabs ---------------------------
__global__ __launch_bounds__(128) void k_ctxred(const float* __restrict__ partial,
                                                float* __restrict__ ctx) {
    int b  = blockIdx.x;
    int eq = threadIdx.x;                 // e = eq*4
    f32x4 a = {0.f, 0.f, 0.f, 0.f};
#pragma unroll
    for (int slab = 0; slab < 8; ++slab)
        a += *(const f32x4*)(partial + ((size_t)b * 8 + slab) * 512 + eq * 4);
    *(f32x4*)(ctx + b * 512 + eq * 4) = a;
}

extern "C" void kernel_launch(void* const* d_in, const int* in_sizes, int n_in,
                              void* d_out, int out_size, void* d_ws, size_t ws_size,
                              hipStream_t stream) {
    const float* enc       = (const float*)d_in[0];
    const float* dec_state = (const float*)d_in[1];
    const float* W_enc     = (const float*)d_in[2];
    const float* W_dec     = (const float*)d_in[3];
    const float* v         = (const float*)d_in[4];

    float* ctx  = (float*)d_out;                 // [64,512]
    float* attn = (float*)d_out + 64 * 512;      // [64,2048] (scores -> softmax in place)

    // workspace: WT bf16 256KB | dp fp32 64KB | partials fp32 1MB
    char*  ws      = (char*)d_ws;
    bf16*  WT      = (bf16*)ws;
    float* dp      = (float*)(ws + 256 * 1024);
    float* partial = (float*)(ws + 256 * 1024 + 64 * 1024);

    k_setup  <<<576, 256, 0, stream>>>(W_enc, dec_state, W_dec, WT, dp);
    k_scores <<<1024, 256, 0, stream>>>(enc, WT, dp, v, attn);
    k_softmax<<<64, 256, 0, stream>>>(attn);
    k_context<<<512, 256, 0, stream>>>(enc, attn, partial);
    k_ctxred <<<64, 128, 0, stream>>>(partial, ctx);
}